// Round 6
// baseline (477.130 us; speedup 1.0000x reference)
//
#include <hip/hip_runtime.h>

// one_layer_gcn: GCNConv(512 -> 1) + ReLU
// out[v] = relu( dinv[v] * ( sum_{(s->v)} h[s]*dinv[s] + h[v]*dinv[v] ) + b )
// h = x @ W, dinv[v] = rsqrt(deg_in_with_selfloop[v])
//
// Round-6 structure (revert to round-4 + ONE change):
//   init_cursor -> FUSED { place (multisplit bucket sort, LDS staging)
//                          || gemv (unscaled h, BW-bound) } interleaved blocks
//   -> deg+scale (per-bucket LDS count, scales hprime in place)
//   -> gather (per-bucket LDS float accum, fused bias+ReLU finalize).
// Rationale: place is LDS/latency-bound (~1.3 TB/s), gemv is pure-BW; the
// graph serializes dispatches, so co-scheduling them in one grid overlaps
// place's idle HBM time with gemv traffic.

#define GCN_D 512
#define NPB 1024          // nodes per bucket
#define NPB_SHIFT 10
#define CHUNK 8192        // edges per place block
#define FT 512            // fused kernel threads
#define CPAD 16           // cursor padding (ints) -> one cacheline per cursor

// ---------------- init per-bucket cursors to b*CAP ----------------
__global__ void init_cursor_kernel(int* __restrict__ cursor, int NB, int CAP) {
    int i = threadIdx.x;
    if (i < NB) cursor[i * CPAD] = i * CAP;
}

// ---------------- FUSED place + gemv ----------------
// place record: (src << NPB_SHIFT) | (dst & (NPB-1))  -- 28 bits for N=200000
__global__ __launch_bounds__(FT) void fused_pg_kernel(
        const int* __restrict__ src, const int* __restrict__ dst,
        int* __restrict__ cursor, unsigned int* __restrict__ packed,
        const float* __restrict__ x, const float* __restrict__ W,
        float* __restrict__ hprime,
        int E, int n, int NB, int CAP, int PB, int P) {
    __shared__ unsigned int staging[CHUNK];
    __shared__ unsigned char bidb[CHUNK];
    __shared__ int hist[256];
    __shared__ int lcur[256];
    __shared__ int delta[256];
    __shared__ int scanbuf[FT];

    const int bid = blockIdx.x;
    const int tid = threadIdx.x;
    const bool is_place = (bid % P == 0) && (bid / P < PB);

    if (is_place) {
        // ---------------- place body (identical to round-4 place) ----------------
        const int pidx = bid / P;
        const int e0 = pidx * CHUNK;
        const int rem = min(CHUNK, E - e0);   // E,CHUNK div by 4 => rem%4==0
        const int r4 = rem >> 2;

        const int4* d4p = reinterpret_cast<const int4*>(dst + e0);
        const int4* s4p = reinterpret_cast<const int4*>(src + e0);

        if (tid < 256) hist[tid] = 0;
        __syncthreads();

        int4 dreg[4];
        #pragma unroll
        for (int k = 0; k < 4; ++k) {
            int i4 = tid + k * FT;
            if (i4 < r4) {
                dreg[k] = d4p[i4];
                atomicAdd(&hist[dreg[k].x >> NPB_SHIFT], 1);
                atomicAdd(&hist[dreg[k].y >> NPB_SHIFT], 1);
                atomicAdd(&hist[dreg[k].z >> NPB_SHIFT], 1);
                atomicAdd(&hist[dreg[k].w >> NPB_SHIFT], 1);
            }
        }
        __syncthreads();

        // inclusive Hillis-Steele over first 256 entries -> exclusive starts
        int c = (tid < NB) ? hist[tid] : 0;
        scanbuf[tid] = c;
        for (int off = 1; off < 256; off <<= 1) {
            __syncthreads();
            int v = (tid >= off) ? scanbuf[tid - off] : 0;
            __syncthreads();
            scanbuf[tid] += v;
        }
        __syncthreads();
        if (tid < NB) {
            int ls = scanbuf[tid] - c;
            lcur[tid] = ls;
            if (c > 0)
                delta[tid] = atomicAdd(&cursor[tid * CPAD], c) - ls;
        }
        __syncthreads();

        #pragma unroll
        for (int k = 0; k < 4; ++k) {
            int i4 = tid + k * FT;
            if (i4 < r4) {
                int4 s4 = s4p[i4];
                int4 d = dreg[k];
                int b, pos;
                b = d.x >> NPB_SHIFT; pos = atomicAdd(&lcur[b], 1);
                staging[pos] = ((unsigned)s4.x << NPB_SHIFT) | (unsigned)(d.x & (NPB - 1));
                bidb[pos] = (unsigned char)b;
                b = d.y >> NPB_SHIFT; pos = atomicAdd(&lcur[b], 1);
                staging[pos] = ((unsigned)s4.y << NPB_SHIFT) | (unsigned)(d.y & (NPB - 1));
                bidb[pos] = (unsigned char)b;
                b = d.z >> NPB_SHIFT; pos = atomicAdd(&lcur[b], 1);
                staging[pos] = ((unsigned)s4.z << NPB_SHIFT) | (unsigned)(d.z & (NPB - 1));
                bidb[pos] = (unsigned char)b;
                b = d.w >> NPB_SHIFT; pos = atomicAdd(&lcur[b], 1);
                staging[pos] = ((unsigned)s4.w << NPB_SHIFT) | (unsigned)(d.w & (NPB - 1));
                bidb[pos] = (unsigned char)b;
            }
        }
        __syncthreads();

        // coalesced copy-out with capacity clamp
        for (int p = tid; p < rem; p += FT) {
            int b = bidb[p];
            int op = p + delta[b];
            if (op < (b + 1) * CAP)       // never hits on-bench (CAP = 2x mean)
                packed[op] = staging[p];
        }
    } else {
        // ---------------- gemv body: 8 waves, 1 row/wave, unscaled ----------------
        int gidx = bid - min(bid / P + 1, PB);   // dense gemv block index
        int wave = tid >> 6;
        int lane = tid & 63;
        int row = gidx * 8 + wave;
        if (row >= n) return;

        const float4* xr = reinterpret_cast<const float4*>(x + (size_t)row * GCN_D);
        const float4* Wv = reinterpret_cast<const float4*>(W);

        float4 a0 = xr[lane];
        float4 w0 = Wv[lane];
        float4 a1 = xr[lane + 64];
        float4 w1 = Wv[lane + 64];

        float dot = a0.x * w0.x + a0.y * w0.y + a0.z * w0.z + a0.w * w0.w
                  + a1.x * w1.x + a1.y * w1.y + a1.z * w1.z + a1.w * w1.w;

        #pragma unroll
        for (int off = 32; off >= 1; off >>= 1)
            dot += __shfl_down(dot, off, 64);

        if (lane == 0) hprime[row] = dot;
    }
}

// ---------------- degree per node + in-place hprime scaling -----------------
__global__ __launch_bounds__(1024) void deg_hp_kernel(const unsigned int* __restrict__ packed,
                                                      const int* __restrict__ cursor,
                                                      int* __restrict__ deg,
                                                      float* __restrict__ hprime,
                                                      int N, int CAP) {
    int b = blockIdx.x;
    __shared__ int acc[NPB];
    for (int i = threadIdx.x; i < NPB; i += blockDim.x) acc[i] = 0;
    __syncthreads();
    int s0 = b * CAP;
    int s1 = min(cursor[b * CPAD], (b + 1) * CAP);
    int cnt = s1 - s0;
    int n4 = cnt >> 2;
    const uint4* p4 = reinterpret_cast<const uint4*>(packed + s0);  // CAP%4==0
    for (int i = threadIdx.x; i < n4; i += blockDim.x) {
        uint4 p = p4[i];
        atomicAdd(&acc[p.x & (NPB - 1)], 1);
        atomicAdd(&acc[p.y & (NPB - 1)], 1);
        atomicAdd(&acc[p.z & (NPB - 1)], 1);
        atomicAdd(&acc[p.w & (NPB - 1)], 1);
    }
    if (threadIdx.x < (cnt & 3))
        atomicAdd(&acc[packed[s0 + (n4 << 2) + threadIdx.x] & (NPB - 1)], 1);
    __syncthreads();
    int node0 = b << NPB_SHIFT;
    for (int j = threadIdx.x; j < NPB; j += blockDim.x) {
        int node = node0 + j;
        if (node < N) {
            int dg = acc[j];
            deg[node] = dg;
            hprime[node] *= rsqrtf((float)(dg + 1));   // h * dinv
        }
    }
}

// ---------------- per-bucket aggregation + fused finalize -------------------
__global__ __launch_bounds__(1024) void gather_kernel(const unsigned int* __restrict__ packed,
                                                      const int* __restrict__ cursor,
                                                      const float* __restrict__ hprime,
                                                      const int* __restrict__ deg,
                                                      const float* __restrict__ bias,
                                                      float* __restrict__ out,
                                                      int N, int CAP) {
    int b = blockIdx.x;
    __shared__ float acc[NPB];
    for (int i = threadIdx.x; i < NPB; i += blockDim.x) acc[i] = 0.f;
    __syncthreads();
    int s0 = b * CAP;
    int s1 = min(cursor[b * CPAD], (b + 1) * CAP);
    int cnt = s1 - s0;
    int n4 = cnt >> 2;
    const uint4* p4 = reinterpret_cast<const uint4*>(packed + s0);
    for (int i = threadIdx.x; i < n4; i += blockDim.x) {
        uint4 p = p4[i];
        atomicAdd(&acc[p.x & (NPB - 1)], hprime[p.x >> NPB_SHIFT]);
        atomicAdd(&acc[p.y & (NPB - 1)], hprime[p.y >> NPB_SHIFT]);
        atomicAdd(&acc[p.z & (NPB - 1)], hprime[p.z >> NPB_SHIFT]);
        atomicAdd(&acc[p.w & (NPB - 1)], hprime[p.w >> NPB_SHIFT]);
    }
    if (threadIdx.x < (cnt & 3)) {
        unsigned p = packed[s0 + (n4 << 2) + threadIdx.x];
        atomicAdd(&acc[p & (NPB - 1)], hprime[p >> NPB_SHIFT]);
    }
    __syncthreads();
    int node0 = b << NPB_SHIFT;
    float bb = bias[0];
    for (int j = threadIdx.x; j < NPB; j += blockDim.x) {
        int node = node0 + j;
        if (node < N) {
            float dinv = rsqrtf((float)(deg[node] + 1));
            float v = dinv * (acc[j] + hprime[node]) + bb;
            out[node] = v > 0.f ? v : 0.f;
        }
    }
}

// ---------------- fallback path (global atomics; used only if ws too small) ----
__global__ void deg_atomic_kernel(const int* __restrict__ dst, int* __restrict__ deg, int e4) {
    int i = blockIdx.x * blockDim.x + threadIdx.x;
    if (i < e4) {
        int4 d = reinterpret_cast<const int4*>(dst)[i];
        atomicAdd(&deg[d.x], 1);
        atomicAdd(&deg[d.y], 1);
        atomicAdd(&deg[d.z], 1);
        atomicAdd(&deg[d.w], 1);
    }
}
__global__ void gemv_scaled_kernel(const float* __restrict__ x, const float* __restrict__ W,
                                   const int* __restrict__ deg, float* __restrict__ hprime, int n) {
    int wave = threadIdx.x >> 6;
    int lane = threadIdx.x & 63;
    int row = blockIdx.x * 4 + wave;
    if (row >= n) return;
    const float4* xr = reinterpret_cast<const float4*>(x + (size_t)row * GCN_D);
    const float4* Wv = reinterpret_cast<const float4*>(W);
    float4 a0 = xr[lane], w0 = Wv[lane];
    float4 a1 = xr[lane + 64], w1 = Wv[lane + 64];
    float dot = a0.x * w0.x + a0.y * w0.y + a0.z * w0.z + a0.w * w0.w
              + a1.x * w1.x + a1.y * w1.y + a1.z * w1.z + a1.w * w1.w;
    #pragma unroll
    for (int off = 32; off >= 1; off >>= 1) dot += __shfl_down(dot, off, 64);
    if (lane == 0) hprime[row] = dot * rsqrtf((float)(deg[row] + 1));
}
__global__ void scatter_kernel(const int* __restrict__ src, const int* __restrict__ dst,
                               const float* __restrict__ hprime, float* __restrict__ acc,
                               int e4) {
    int i = blockIdx.x * blockDim.x + threadIdx.x;
    if (i < e4) {
        int4 s = reinterpret_cast<const int4*>(src)[i];
        int4 d = reinterpret_cast<const int4*>(dst)[i];
        atomicAdd(&acc[d.x], hprime[s.x]);
        atomicAdd(&acc[d.y], hprime[s.y]);
        atomicAdd(&acc[d.z], hprime[s.z]);
        atomicAdd(&acc[d.w], hprime[s.w]);
    }
}
__global__ void final_kernel(const float* __restrict__ hprime, const float* __restrict__ accg,
                             const int* __restrict__ deg, const float* __restrict__ bptr,
                             float* __restrict__ out, int n) {
    int i = blockIdx.x * blockDim.x + threadIdx.x;
    if (i < n) {
        float dinv = rsqrtf((float)(deg[i] + 1));
        float v = dinv * (accg[i] + hprime[i]) + bptr[0];
        out[i] = v > 0.0f ? v : 0.0f;
    }
}

extern "C" void kernel_launch(void* const* d_in, const int* in_sizes, int n_in,
                              void* d_out, int out_size, void* d_ws, size_t ws_size,
                              hipStream_t stream) {
    const float* x    = (const float*)d_in[0];
    const int*   ei   = (const int*)d_in[1];   // [2, E]: row0 = src, row1 = dst
    const float* W    = (const float*)d_in[2];
    const float* bias = (const float*)d_in[3];
    float* out = (float*)d_out;

    const int n = in_sizes[0] / GCN_D;         // 200000
    const int E = in_sizes[1] / 2;             // 12800000
    const int e4 = E / 4;

    const int* src = ei;
    const int* dst = ei + E;

    const int NB = (n + NPB - 1) >> NPB_SHIFT; // 196

    // ws layout: deg[n] | hprime[n] | acc_fb[n] | cursor[NB*CPAD] | packed[NB*CAP]
    auto align64 = [](size_t v) { return (v + 63) & ~(size_t)63; };
    size_t off_deg    = 0;
    size_t off_hprime = align64(off_deg    + (size_t)n * 4);
    size_t off_accfb  = align64(off_hprime + (size_t)n * 4);
    size_t off_cursor = align64(off_accfb  + (size_t)n * 4);
    size_t off_packed = align64(off_cursor + (size_t)NB * CPAD * 4);

    char* ws = (char*)d_ws;
    int*   deg    = (int*)(ws + off_deg);
    float* hprime = (float*)(ws + off_hprime);

    // bucket capacity from available workspace (target 2x mean load)
    int CAP = 0;
    if (ws_size > off_packed) {
        size_t cap_avail = (ws_size - off_packed) / ((size_t)NB * 4);
        CAP = (int)(cap_avail > 131072 ? 131072 : cap_avail) & ~3;  // multiple of 4
    }
    const int mean_load = (int)(((long long)E + NB - 1) / NB);

    if (NB <= 256 && CAP >= mean_load + mean_load / 32) {   // >= ~8 sigma headroom
        int* cursor = (int*)(ws + off_cursor);
        unsigned int* packed = (unsigned int*)(ws + off_packed);

        const int PB = (E + CHUNK - 1) / CHUNK;       // 1563 place blocks
        const int GB = (n + 7) / 8;                   // 25000 gemv blocks (8 rows each)
        const int R  = PB + GB;
        int P = R / PB; if (P < 1) P = 1;             // interleave period (16)

        init_cursor_kernel<<<1, 256, 0, stream>>>(cursor, NB, CAP);
        fused_pg_kernel<<<R, FT, 0, stream>>>(src, dst, cursor, packed,
                                              x, W, hprime, E, n, NB, CAP, PB, P);
        deg_hp_kernel<<<NB, 1024, 0, stream>>>(packed, cursor, deg, hprime, n, CAP);
        gather_kernel<<<NB, 1024, 0, stream>>>(packed, cursor, hprime, deg, bias, out, n, CAP);
    } else {
        // fallback: atomic path (slow but correct, tiny ws)
        float* accfb = (float*)(ws + off_accfb);
        hipMemsetAsync(ws, 0, off_cursor, stream);    // zero deg + hprime + accfb
        deg_atomic_kernel<<<(e4 + 255) / 256, 256, 0, stream>>>(dst, deg, e4);
        gemv_scaled_kernel<<<(n + 3) / 4, 256, 0, stream>>>(x, W, deg, hprime, n);
        scatter_kernel<<<(e4 + 255) / 256, 256, 0, stream>>>(src, dst, hprime, accfb, e4);
        final_kernel<<<(n + 255) / 256, 256, 0, stream>>>(hprime, accfb, deg, bias, out, n);
    }
}

// Round 7
// 277.385 us; speedup vs baseline: 1.7201x; 1.7201x over previous
//
#include <hip/hip_runtime.h>

// one_layer_gcn: GCNConv(512 -> 1) + ReLU
// out[v] = relu( dinv[v] * ( sum_{(s->v)} h[s]*dinv[s] + h[v]*dinv[v] ) + b )
// h = x @ W, dinv[v] = rsqrt(deg_in_with_selfloop[v])
//
// Round-7: round-4 pipeline (separate kernels — fusing place+gemv regressed:
// gemv blocks inherit the 45KB LDS footprint -> 19% occupancy), with:
//  * place rewritten: fixed 64-slot LDS region per bucket + spill path,
//    no histogram, no scan (LDS ops/edge ~7 -> ~3.5, barriers 10 -> 2)
//  * gemv: persistent grid-stride waves (amortize wave setup, pipeline loads)

#define GCN_D 512
#define NPB 1024          // nodes per bucket
#define NPB_SHIFT 10
#define CHUNK 8192        // edges per place block
#define PT 512            // place block threads (8 waves)
#define SLOTS 64          // LDS staging slots per bucket (spill if exceeded)
#define CPAD 16           // cursor padding (ints) -> one cacheline per cursor

// ---------------- init per-bucket cursors to b*CAP ----------------
__global__ void init_cursor_kernel(int* __restrict__ cursor, int NB, int CAP) {
    for (int i = threadIdx.x; i < NB; i += blockDim.x)
        cursor[i * CPAD] = i * CAP;
}

// ---------------- place: fixed-cap LDS bucket staging + spill ----------------
// record: (src << NPB_SHIFT) | (dst & (NPB-1))  -- fits 32b for N <= 4M
__global__ __launch_bounds__(PT) void place_kernel(const int* __restrict__ src,
                                                   const int* __restrict__ dst,
                                                   int* __restrict__ cursor,
                                                   unsigned int* __restrict__ packed,
                                                   int E, int NB, int CAP) {
    extern __shared__ int smem[];
    unsigned int* staging = (unsigned int*)smem;   // [NB * SLOTS]
    int* lcur = smem + NB * SLOTS;                 // [NB]

    const int tid = threadIdx.x;
    const int e0 = blockIdx.x * CHUNK;
    const int rem = min(CHUNK, E - e0);            // E,CHUNK div by 4 => rem%4==0
    const int r4 = rem >> 2;

    const int4* d4p = reinterpret_cast<const int4*>(dst + e0);
    const int4* s4p = reinterpret_cast<const int4*>(src + e0);

    for (int i = tid; i < NB; i += PT) lcur[i] = 0;
    __syncthreads();

    #pragma unroll
    for (int k = 0; k < 4; ++k) {
        int i4 = tid + k * PT;
        if (i4 < r4) {
            int4 d = d4p[i4];
            int4 s = s4p[i4];
            int b, pos;
            unsigned rec;
            #define PLACE_ONE(DC, SC)                                            \
                b = (DC) >> NPB_SHIFT;                                           \
                rec = ((unsigned)(SC) << NPB_SHIFT) | (unsigned)((DC) & (NPB-1));\
                pos = atomicAdd(&lcur[b], 1);                                    \
                if (pos < SLOTS) staging[(b << 6) + pos] = rec;                  \
                else {  /* rare spill: direct global slot */                     \
                    int gp = atomicAdd(&cursor[b * CPAD], 1);                    \
                    if (gp < (b + 1) * CAP) packed[gp] = rec;                    \
                }
            PLACE_ONE(d.x, s.x)
            PLACE_ONE(d.y, s.y)
            PLACE_ONE(d.z, s.z)
            PLACE_ONE(d.w, s.w)
            #undef PLACE_ONE
        }
    }
    __syncthreads();

    // copy-out: one wave per bucket (strided); coalesced run stores
    const int wid = tid >> 6;
    const int lane = tid & 63;
    const int nw = PT >> 6;                        // 8 waves
    for (int b = wid; b < NB; b += nw) {
        int cnt = lcur[b];
        if (cnt > SLOTS) cnt = SLOTS;              // spilled ones already written
        if (cnt == 0) continue;
        int base = 0;
        if (lane == 0) base = atomicAdd(&cursor[b * CPAD], cnt);
        base = __shfl(base, 0, 64);
        if (lane < cnt) {
            int gp = base + lane;
            if (gp < (b + 1) * CAP)                // capacity clamp (off-bench only)
                packed[gp] = staging[(b << 6) + lane];
        }
    }
}

// ---------------- GEMV: persistent grid-stride waves, unscaled h --------------
__global__ __launch_bounds__(1024) void gemv_kernel(const float* __restrict__ x,
                                                    const float* __restrict__ W,
                                                    float* __restrict__ hprime, int n) {
    const int lane = threadIdx.x & 63;
    const int gw = blockIdx.x * (blockDim.x >> 6) + (threadIdx.x >> 6);
    const int stride = gridDim.x * (blockDim.x >> 6);

    const float4* Wv = reinterpret_cast<const float4*>(W);
    const float4 w0 = Wv[lane];
    const float4 w1 = Wv[lane + 64];

    for (int row = gw; row < n; row += stride) {
        const float4* xr = reinterpret_cast<const float4*>(x + (size_t)row * GCN_D);
        float4 a0 = xr[lane];
        float4 a1 = xr[lane + 64];
        float dot = a0.x * w0.x + a0.y * w0.y + a0.z * w0.z + a0.w * w0.w
                  + a1.x * w1.x + a1.y * w1.y + a1.z * w1.z + a1.w * w1.w;
        #pragma unroll
        for (int off = 32; off >= 1; off >>= 1)
            dot += __shfl_down(dot, off, 64);
        if (lane == 0) hprime[row] = dot;
    }
}

// ---------------- degree per node + in-place hprime scaling -----------------
__global__ __launch_bounds__(1024) void deg_hp_kernel(const unsigned int* __restrict__ packed,
                                                      const int* __restrict__ cursor,
                                                      int* __restrict__ deg,
                                                      float* __restrict__ hprime,
                                                      int N, int CAP) {
    int b = blockIdx.x;
    __shared__ int acc[NPB];
    for (int i = threadIdx.x; i < NPB; i += blockDim.x) acc[i] = 0;
    __syncthreads();
    int s0 = b * CAP;
    int s1 = min(cursor[b * CPAD], (b + 1) * CAP);
    int cnt = s1 - s0;
    int n4 = cnt >> 2;
    const uint4* p4 = reinterpret_cast<const uint4*>(packed + s0);  // CAP%4==0
    for (int i = threadIdx.x; i < n4; i += blockDim.x) {
        uint4 p = p4[i];
        atomicAdd(&acc[p.x & (NPB - 1)], 1);
        atomicAdd(&acc[p.y & (NPB - 1)], 1);
        atomicAdd(&acc[p.z & (NPB - 1)], 1);
        atomicAdd(&acc[p.w & (NPB - 1)], 1);
    }
    if (threadIdx.x < (cnt & 3))
        atomicAdd(&acc[packed[s0 + (n4 << 2) + threadIdx.x] & (NPB - 1)], 1);
    __syncthreads();
    int node0 = b << NPB_SHIFT;
    for (int j = threadIdx.x; j < NPB; j += blockDim.x) {
        int node = node0 + j;
        if (node < N) {
            int dg = acc[j];
            deg[node] = dg;
            hprime[node] *= rsqrtf((float)(dg + 1));   // h * dinv
        }
    }
}

// ---------------- per-bucket aggregation + fused finalize -------------------
__global__ __launch_bounds__(1024) void gather_kernel(const unsigned int* __restrict__ packed,
                                                      const int* __restrict__ cursor,
                                                      const float* __restrict__ hprime,
                                                      const int* __restrict__ deg,
                                                      const float* __restrict__ bias,
                                                      float* __restrict__ out,
                                                      int N, int CAP) {
    int b = blockIdx.x;
    __shared__ float acc[NPB];
    for (int i = threadIdx.x; i < NPB; i += blockDim.x) acc[i] = 0.f;
    __syncthreads();
    int s0 = b * CAP;
    int s1 = min(cursor[b * CPAD], (b + 1) * CAP);
    int cnt = s1 - s0;
    int n4 = cnt >> 2;
    const uint4* p4 = reinterpret_cast<const uint4*>(packed + s0);
    for (int i = threadIdx.x; i < n4; i += blockDim.x) {
        uint4 p = p4[i];
        atomicAdd(&acc[p.x & (NPB - 1)], hprime[p.x >> NPB_SHIFT]);
        atomicAdd(&acc[p.y & (NPB - 1)], hprime[p.y >> NPB_SHIFT]);
        atomicAdd(&acc[p.z & (NPB - 1)], hprime[p.z >> NPB_SHIFT]);
        atomicAdd(&acc[p.w & (NPB - 1)], hprime[p.w >> NPB_SHIFT]);
    }
    if (threadIdx.x < (cnt & 3)) {
        unsigned p = packed[s0 + (n4 << 2) + threadIdx.x];
        atomicAdd(&acc[p & (NPB - 1)], hprime[p >> NPB_SHIFT]);
    }
    __syncthreads();
    int node0 = b << NPB_SHIFT;
    float bb = bias[0];
    for (int j = threadIdx.x; j < NPB; j += blockDim.x) {
        int node = node0 + j;
        if (node < N) {
            float dinv = rsqrtf((float)(deg[node] + 1));
            float v = dinv * (acc[j] + hprime[node]) + bb;
            out[node] = v > 0.f ? v : 0.f;
        }
    }
}

// ---------------- fallback path (global atomics; used only if ws too small) ----
__global__ void deg_atomic_kernel(const int* __restrict__ dst, int* __restrict__ deg, int e4) {
    int i = blockIdx.x * blockDim.x + threadIdx.x;
    if (i < e4) {
        int4 d = reinterpret_cast<const int4*>(dst)[i];
        atomicAdd(&deg[d.x], 1);
        atomicAdd(&deg[d.y], 1);
        atomicAdd(&deg[d.z], 1);
        atomicAdd(&deg[d.w], 1);
    }
}
__global__ void gemv_scaled_kernel(const float* __restrict__ x, const float* __restrict__ W,
                                   const int* __restrict__ deg, float* __restrict__ hprime, int n) {
    int wave = threadIdx.x >> 6;
    int lane = threadIdx.x & 63;
    int row = blockIdx.x * 4 + wave;
    if (row >= n) return;
    const float4* xr = reinterpret_cast<const float4*>(x + (size_t)row * GCN_D);
    const float4* Wv = reinterpret_cast<const float4*>(W);
    float4 a0 = xr[lane], w0 = Wv[lane];
    float4 a1 = xr[lane + 64], w1 = Wv[lane + 64];
    float dot = a0.x * w0.x + a0.y * w0.y + a0.z * w0.z + a0.w * w0.w
              + a1.x * w1.x + a1.y * w1.y + a1.z * w1.z + a1.w * w1.w;
    #pragma unroll
    for (int off = 32; off >= 1; off >>= 1) dot += __shfl_down(dot, off, 64);
    if (lane == 0) hprime[row] = dot * rsqrtf((float)(deg[row] + 1));
}
__global__ void scatter_kernel(const int* __restrict__ src, const int* __restrict__ dst,
                               const float* __restrict__ hprime, float* __restrict__ acc,
                               int e4) {
    int i = blockIdx.x * blockDim.x + threadIdx.x;
    if (i < e4) {
        int4 s = reinterpret_cast<const int4*>(src)[i];
        int4 d = reinterpret_cast<const int4*>(dst)[i];
        atomicAdd(&acc[d.x], hprime[s.x]);
        atomicAdd(&acc[d.y], hprime[s.y]);
        atomicAdd(&acc[d.z], hprime[s.z]);
        atomicAdd(&acc[d.w], hprime[s.w]);
    }
}
__global__ void final_kernel(const float* __restrict__ hprime, const float* __restrict__ accg,
                             const int* __restrict__ deg, const float* __restrict__ bptr,
                             float* __restrict__ out, int n) {
    int i = blockIdx.x * blockDim.x + threadIdx.x;
    if (i < n) {
        float dinv = rsqrtf((float)(deg[i] + 1));
        float v = dinv * (accg[i] + hprime[i]) + bptr[0];
        out[i] = v > 0.0f ? v : 0.0f;
    }
}

extern "C" void kernel_launch(void* const* d_in, const int* in_sizes, int n_in,
                              void* d_out, int out_size, void* d_ws, size_t ws_size,
                              hipStream_t stream) {
    const float* x    = (const float*)d_in[0];
    const int*   ei   = (const int*)d_in[1];   // [2, E]: row0 = src, row1 = dst
    const float* W    = (const float*)d_in[2];
    const float* bias = (const float*)d_in[3];
    float* out = (float*)d_out;

    const int n = in_sizes[0] / GCN_D;         // 200000
    const int E = in_sizes[1] / 2;             // 12800000
    const int e4 = E / 4;

    const int* src = ei;
    const int* dst = ei + E;

    const int NB = (n + NPB - 1) >> NPB_SHIFT; // 196

    // ws layout: deg[n] | hprime[n] | acc_fb[n] | cursor[NB*CPAD] | packed[NB*CAP]
    auto align64 = [](size_t v) { return (v + 63) & ~(size_t)63; };
    size_t off_deg    = 0;
    size_t off_hprime = align64(off_deg    + (size_t)n * 4);
    size_t off_accfb  = align64(off_hprime + (size_t)n * 4);
    size_t off_cursor = align64(off_accfb  + (size_t)n * 4);
    size_t off_packed = align64(off_cursor + (size_t)NB * CPAD * 4);

    char* ws = (char*)d_ws;
    int*   deg    = (int*)(ws + off_deg);
    float* hprime = (float*)(ws + off_hprime);

    // bucket capacity from available workspace (target 2x mean load)
    int CAP = 0;
    if (ws_size > off_packed) {
        size_t cap_avail = (ws_size - off_packed) / ((size_t)NB * 4);
        CAP = (int)(cap_avail > 131072 ? 131072 : cap_avail) & ~3;  // multiple of 4
    }
    const int mean_load = (int)(((long long)E + NB - 1) / NB);
    const size_t place_lds = (size_t)(NB * SLOTS + NB) * sizeof(int);  // ~51.7 KB

    if (NB <= 256 && CAP >= mean_load + mean_load / 32 && place_lds <= 64 * 1024) {
        int* cursor = (int*)(ws + off_cursor);
        unsigned int* packed = (unsigned int*)(ws + off_packed);

        init_cursor_kernel<<<1, 256, 0, stream>>>(cursor, NB, CAP);
        place_kernel<<<(E + CHUNK - 1) / CHUNK, PT, place_lds, stream>>>(
            src, dst, cursor, packed, E, NB, CAP);
        gemv_kernel<<<1024, 1024, 0, stream>>>(x, W, hprime, n);
        deg_hp_kernel<<<NB, 1024, 0, stream>>>(packed, cursor, deg, hprime, n, CAP);
        gather_kernel<<<NB, 1024, 0, stream>>>(packed, cursor, hprime, deg, bias, out, n, CAP);
    } else {
        // fallback: atomic path (slow but correct, tiny ws)
        float* accfb = (float*)(ws + off_accfb);
        hipMemsetAsync(ws, 0, off_cursor, stream);    // zero deg + hprime + accfb
        deg_atomic_kernel<<<(e4 + 255) / 256, 256, 0, stream>>>(dst, deg, e4);
        gemv_scaled_kernel<<<(n + 3) / 4, 256, 0, stream>>>(x, W, deg, hprime, n);
        scatter_kernel<<<(e4 + 255) / 256, 256, 0, stream>>>(src, dst, hprime, accfb, e4);
        final_kernel<<<(n + 255) / 256, 256, 0, stream>>>(hprime, accfb, deg, bias, out, n);
    }
}

// Round 8
// 258.653 us; speedup vs baseline: 1.8447x; 1.0724x over previous
//
#include <hip/hip_runtime.h>

// one_layer_gcn: GCNConv(512 -> 1) + ReLU
// out[v] = relu( dinv[v] * ( sum_{(s->v)} h[s]*dinv[s] + h[v]*dinv[v] ) + b )
// h = x @ W, dinv[v] = rsqrt(deg_in_with_selfloop[v])
//
// Round-8 = round-4 pipeline verbatim (best so far, 249us) with ONE change:
// gemv is now persistent grid-stride, 2 rows/wave/iter, with next-iteration
// loads issued BEFORE the shuffle-reduce chain (overlap ~600cy reduce with
// ~900cy HBM latency -> keep memory pipe full).

#define GCN_D 512
#define NPB 1024          // nodes per bucket
#define NPB_SHIFT 10
#define CHUNK 8192        // edges per place block
#define PT 512            // place block threads
#define CPAD 16           // cursor padding (ints) -> one cacheline per cursor

// ---------------- init per-bucket cursors to b*CAP ----------------
__global__ void init_cursor_kernel(int* __restrict__ cursor, int NB, int CAP) {
    int i = threadIdx.x;
    if (i < NB) cursor[i * CPAD] = i * CAP;
}

// ---------------- multisplit place with LDS staging (round-4 version) ---------
// record: (src << NPB_SHIFT) | (dst & (NPB-1))  -- 28 bits for N=200000
__global__ __launch_bounds__(PT) void place_kernel(const int* __restrict__ src,
                                                   const int* __restrict__ dst,
                                                   int* __restrict__ cursor,
                                                   unsigned int* __restrict__ packed,
                                                   int E, int NB, int CAP) {
    __shared__ unsigned int staging[CHUNK];
    __shared__ unsigned char bid[CHUNK];
    __shared__ int hist[256];
    __shared__ int lcur[256];
    __shared__ int delta[256];
    __shared__ int scanbuf[PT];

    const int tid = threadIdx.x;
    const int e0 = blockIdx.x * CHUNK;
    const int rem = min(CHUNK, E - e0);     // E,CHUNK divisible by 4 => rem%4==0
    const int r4 = rem >> 2;

    const int4* d4p = reinterpret_cast<const int4*>(dst + e0);
    const int4* s4p = reinterpret_cast<const int4*>(src + e0);

    if (tid < 256) hist[tid] = 0;
    __syncthreads();

    int4 dreg[4];
    #pragma unroll
    for (int k = 0; k < 4; ++k) {
        int i4 = tid + k * PT;
        if (i4 < r4) {
            dreg[k] = d4p[i4];
            atomicAdd(&hist[dreg[k].x >> NPB_SHIFT], 1);
            atomicAdd(&hist[dreg[k].y >> NPB_SHIFT], 1);
            atomicAdd(&hist[dreg[k].z >> NPB_SHIFT], 1);
            atomicAdd(&hist[dreg[k].w >> NPB_SHIFT], 1);
        }
    }
    __syncthreads();

    // exclusive scan of hist[0..NB) via inclusive Hillis-Steele - c
    int c = (tid < NB) ? hist[tid] : 0;
    scanbuf[tid] = c;
    for (int off = 1; off < 256; off <<= 1) {
        __syncthreads();
        int v = (tid >= off) ? scanbuf[tid - off] : 0;
        __syncthreads();
        scanbuf[tid] += v;
    }
    __syncthreads();
    if (tid < NB) {
        int ls = scanbuf[tid] - c;        // local exclusive start
        lcur[tid] = ls;
        if (c > 0)
            delta[tid] = atomicAdd(&cursor[tid * CPAD], c) - ls;
    }
    __syncthreads();

    // place into LDS staging ordered by bucket
    #pragma unroll
    for (int k = 0; k < 4; ++k) {
        int i4 = tid + k * PT;
        if (i4 < r4) {
            int4 s4 = s4p[i4];
            int4 d = dreg[k];
            int b, pos;
            b = d.x >> NPB_SHIFT; pos = atomicAdd(&lcur[b], 1);
            staging[pos] = ((unsigned)s4.x << NPB_SHIFT) | (unsigned)(d.x & (NPB - 1));
            bid[pos] = (unsigned char)b;
            b = d.y >> NPB_SHIFT; pos = atomicAdd(&lcur[b], 1);
            staging[pos] = ((unsigned)s4.y << NPB_SHIFT) | (unsigned)(d.y & (NPB - 1));
            bid[pos] = (unsigned char)b;
            b = d.z >> NPB_SHIFT; pos = atomicAdd(&lcur[b], 1);
            staging[pos] = ((unsigned)s4.z << NPB_SHIFT) | (unsigned)(d.z & (NPB - 1));
            bid[pos] = (unsigned char)b;
            b = d.w >> NPB_SHIFT; pos = atomicAdd(&lcur[b], 1);
            staging[pos] = ((unsigned)s4.w << NPB_SHIFT) | (unsigned)(d.w & (NPB - 1));
            bid[pos] = (unsigned char)b;
        }
    }
    __syncthreads();

    // coalesced copy-out: consecutive p -> consecutive addresses within a run
    for (int p = tid; p < rem; p += PT) {
        int b = bid[p];
        int op = p + delta[b];
        if (op < (b + 1) * CAP)           // capacity clamp (never hits on-bench)
            packed[op] = staging[p];
    }
}

// ---------------- GEMV: persistent, 2 rows/wave/iter, prefetched --------------
__global__ __launch_bounds__(256) void gemv_kernel(const float* __restrict__ x,
                                                   const float* __restrict__ W,
                                                   float* __restrict__ hprime, int n) {
    const int lane = threadIdx.x & 63;
    const int gw = blockIdx.x * 4 + (threadIdx.x >> 6);
    const int nwaves = gridDim.x * 4;
    const int stride = nwaves * 2;

    const float4* Wv = reinterpret_cast<const float4*>(W);
    const float4 w0 = Wv[lane];
    const float4 w1 = Wv[lane + 64];

    int row = gw * 2;
    if (row >= n) return;

    // load current pair (guard second row)
    const float4* xr = reinterpret_cast<const float4*>(x + (size_t)row * GCN_D);
    float4 a0 = xr[lane], a1 = xr[lane + 64];
    float4 b0, b1;
    bool has2 = (row + 1 < n);
    if (has2) {
        const float4* xs = reinterpret_cast<const float4*>(x + (size_t)(row + 1) * GCN_D);
        b0 = xs[lane]; b1 = xs[lane + 64];
    }

    for (;;) {
        int nxt = row + stride;
        // ---- issue next-iteration loads BEFORE the reduce chain ----
        float4 c0, c1, d0, d1;
        bool nhas1 = (nxt < n), nhas2 = (nxt + 1 < n);
        if (nhas1) {
            const float4* xn = reinterpret_cast<const float4*>(x + (size_t)nxt * GCN_D);
            c0 = xn[lane]; c1 = xn[lane + 64];
        }
        if (nhas2) {
            const float4* xm = reinterpret_cast<const float4*>(x + (size_t)(nxt + 1) * GCN_D);
            d0 = xm[lane]; d1 = xm[lane + 64];
        }
        // ---- reduce current pair (overlaps the in-flight loads) ----
        float dot0 = a0.x * w0.x + a0.y * w0.y + a0.z * w0.z + a0.w * w0.w
                   + a1.x * w1.x + a1.y * w1.y + a1.z * w1.z + a1.w * w1.w;
        #pragma unroll
        for (int off = 32; off >= 1; off >>= 1)
            dot0 += __shfl_down(dot0, off, 64);
        if (lane == 0) hprime[row] = dot0;
        if (has2) {
            float dot1 = b0.x * w0.x + b0.y * w0.y + b0.z * w0.z + b0.w * w0.w
                       + b1.x * w1.x + b1.y * w1.y + b1.z * w1.z + b1.w * w1.w;
            #pragma unroll
            for (int off = 32; off >= 1; off >>= 1)
                dot1 += __shfl_down(dot1, off, 64);
            if (lane == 0) hprime[row + 1] = dot1;
        }
        if (!nhas1) break;
        a0 = c0; a1 = c1;
        b0 = d0; b1 = d1;
        has2 = nhas2;
        row = nxt;
    }
}

// ---------------- degree per node + in-place hprime scaling -----------------
__global__ __launch_bounds__(1024) void deg_hp_kernel(const unsigned int* __restrict__ packed,
                                                      const int* __restrict__ cursor,
                                                      int* __restrict__ deg,
                                                      float* __restrict__ hprime,
                                                      int N, int CAP) {
    int b = blockIdx.x;
    __shared__ int acc[NPB];
    for (int i = threadIdx.x; i < NPB; i += blockDim.x) acc[i] = 0;
    __syncthreads();
    int s0 = b * CAP;
    int s1 = min(cursor[b * CPAD], (b + 1) * CAP);
    int cnt = s1 - s0;
    int n4 = cnt >> 2;
    const uint4* p4 = reinterpret_cast<const uint4*>(packed + s0);  // CAP%4==0
    for (int i = threadIdx.x; i < n4; i += blockDim.x) {
        uint4 p = p4[i];
        atomicAdd(&acc[p.x & (NPB - 1)], 1);
        atomicAdd(&acc[p.y & (NPB - 1)], 1);
        atomicAdd(&acc[p.z & (NPB - 1)], 1);
        atomicAdd(&acc[p.w & (NPB - 1)], 1);
    }
    if (threadIdx.x < (cnt & 3))
        atomicAdd(&acc[packed[s0 + (n4 << 2) + threadIdx.x] & (NPB - 1)], 1);
    __syncthreads();
    int node0 = b << NPB_SHIFT;
    for (int j = threadIdx.x; j < NPB; j += blockDim.x) {
        int node = node0 + j;
        if (node < N) {
            int dg = acc[j];
            deg[node] = dg;
            hprime[node] *= rsqrtf((float)(dg + 1));   // h * dinv
        }
    }
}

// ---------------- per-bucket aggregation + fused finalize -------------------
__global__ __launch_bounds__(1024) void gather_kernel(const unsigned int* __restrict__ packed,
                                                      const int* __restrict__ cursor,
                                                      const float* __restrict__ hprime,
                                                      const int* __restrict__ deg,
                                                      const float* __restrict__ bias,
                                                      float* __restrict__ out,
                                                      int N, int CAP) {
    int b = blockIdx.x;
    __shared__ float acc[NPB];
    for (int i = threadIdx.x; i < NPB; i += blockDim.x) acc[i] = 0.f;
    __syncthreads();
    int s0 = b * CAP;
    int s1 = min(cursor[b * CPAD], (b + 1) * CAP);
    int cnt = s1 - s0;
    int n4 = cnt >> 2;
    const uint4* p4 = reinterpret_cast<const uint4*>(packed + s0);
    for (int i = threadIdx.x; i < n4; i += blockDim.x) {
        uint4 p = p4[i];
        atomicAdd(&acc[p.x & (NPB - 1)], hprime[p.x >> NPB_SHIFT]);
        atomicAdd(&acc[p.y & (NPB - 1)], hprime[p.y >> NPB_SHIFT]);
        atomicAdd(&acc[p.z & (NPB - 1)], hprime[p.z >> NPB_SHIFT]);
        atomicAdd(&acc[p.w & (NPB - 1)], hprime[p.w >> NPB_SHIFT]);
    }
    if (threadIdx.x < (cnt & 3)) {
        unsigned p = packed[s0 + (n4 << 2) + threadIdx.x];
        atomicAdd(&acc[p & (NPB - 1)], hprime[p >> NPB_SHIFT]);
    }
    __syncthreads();
    int node0 = b << NPB_SHIFT;
    float bb = bias[0];
    for (int j = threadIdx.x; j < NPB; j += blockDim.x) {
        int node = node0 + j;
        if (node < N) {
            float dinv = rsqrtf((float)(deg[node] + 1));
            float v = dinv * (acc[j] + hprime[node]) + bb;
            out[node] = v > 0.f ? v : 0.f;
        }
    }
}

// ---------------- fallback path (global atomics; used only if ws too small) ----
__global__ void deg_atomic_kernel(const int* __restrict__ dst, int* __restrict__ deg, int e4) {
    int i = blockIdx.x * blockDim.x + threadIdx.x;
    if (i < e4) {
        int4 d = reinterpret_cast<const int4*>(dst)[i];
        atomicAdd(&deg[d.x], 1);
        atomicAdd(&deg[d.y], 1);
        atomicAdd(&deg[d.z], 1);
        atomicAdd(&deg[d.w], 1);
    }
}
__global__ void gemv_scaled_kernel(const float* __restrict__ x, const float* __restrict__ W,
                                   const int* __restrict__ deg, float* __restrict__ hprime, int n) {
    int wave = threadIdx.x >> 6;
    int lane = threadIdx.x & 63;
    int row = blockIdx.x * 4 + wave;
    if (row >= n) return;
    const float4* xr = reinterpret_cast<const float4*>(x + (size_t)row * GCN_D);
    const float4* Wv = reinterpret_cast<const float4*>(W);
    float4 a0 = xr[lane], w0 = Wv[lane];
    float4 a1 = xr[lane + 64], w1 = Wv[lane + 64];
    float dot = a0.x * w0.x + a0.y * w0.y + a0.z * w0.z + a0.w * w0.w
              + a1.x * w1.x + a1.y * w1.y + a1.z * w1.z + a1.w * w1.w;
    #pragma unroll
    for (int off = 32; off >= 1; off >>= 1) dot += __shfl_down(dot, off, 64);
    if (lane == 0) hprime[row] = dot * rsqrtf((float)(deg[row] + 1));
}
__global__ void scatter_kernel(const int* __restrict__ src, const int* __restrict__ dst,
                               const float* __restrict__ hprime, float* __restrict__ acc,
                               int e4) {
    int i = blockIdx.x * blockDim.x + threadIdx.x;
    if (i < e4) {
        int4 s = reinterpret_cast<const int4*>(src)[i];
        int4 d = reinterpret_cast<const int4*>(dst)[i];
        atomicAdd(&acc[d.x], hprime[s.x]);
        atomicAdd(&acc[d.y], hprime[s.y]);
        atomicAdd(&acc[d.z], hprime[s.z]);
        atomicAdd(&acc[d.w], hprime[s.w]);
    }
}
__global__ void final_kernel(const float* __restrict__ hprime, const float* __restrict__ accg,
                             const int* __restrict__ deg, const float* __restrict__ bptr,
                             float* __restrict__ out, int n) {
    int i = blockIdx.x * blockDim.x + threadIdx.x;
    if (i < n) {
        float dinv = rsqrtf((float)(deg[i] + 1));
        float v = dinv * (accg[i] + hprime[i]) + bptr[0];
        out[i] = v > 0.0f ? v : 0.0f;
    }
}

extern "C" void kernel_launch(void* const* d_in, const int* in_sizes, int n_in,
                              void* d_out, int out_size, void* d_ws, size_t ws_size,
                              hipStream_t stream) {
    const float* x    = (const float*)d_in[0];
    const int*   ei   = (const int*)d_in[1];   // [2, E]: row0 = src, row1 = dst
    const float* W    = (const float*)d_in[2];
    const float* bias = (const float*)d_in[3];
    float* out = (float*)d_out;

    const int n = in_sizes[0] / GCN_D;         // 200000
    const int E = in_sizes[1] / 2;             // 12800000
    const int e4 = E / 4;

    const int* src = ei;
    const int* dst = ei + E;

    const int NB = (n + NPB - 1) >> NPB_SHIFT; // 196

    // ws layout: deg[n] | hprime[n] | acc_fb[n] | cursor[NB*CPAD] | packed[NB*CAP]
    auto align64 = [](size_t v) { return (v + 63) & ~(size_t)63; };
    size_t off_deg    = 0;
    size_t off_hprime = align64(off_deg    + (size_t)n * 4);
    size_t off_accfb  = align64(off_hprime + (size_t)n * 4);
    size_t off_cursor = align64(off_accfb  + (size_t)n * 4);
    size_t off_packed = align64(off_cursor + (size_t)NB * CPAD * 4);

    char* ws = (char*)d_ws;
    int*   deg    = (int*)(ws + off_deg);
    float* hprime = (float*)(ws + off_hprime);

    // bucket capacity from available workspace (target 2x mean load)
    int CAP = 0;
    if (ws_size > off_packed) {
        size_t cap_avail = (ws_size - off_packed) / ((size_t)NB * 4);
        CAP = (int)(cap_avail > 131072 ? 131072 : cap_avail) & ~3;  // multiple of 4
    }
    const int mean_load = (int)(((long long)E + NB - 1) / NB);

    if (NB <= 256 && CAP >= mean_load + mean_load / 32) {   // >= ~8 sigma headroom
        int* cursor = (int*)(ws + off_cursor);
        unsigned int* packed = (unsigned int*)(ws + off_packed);

        init_cursor_kernel<<<1, 256, 0, stream>>>(cursor, NB, CAP);
        place_kernel<<<(E + CHUNK - 1) / CHUNK, PT, 0, stream>>>(src, dst, cursor, packed, E, NB, CAP);
        gemv_kernel<<<2048, 256, 0, stream>>>(x, W, hprime, n);
        deg_hp_kernel<<<NB, 1024, 0, stream>>>(packed, cursor, deg, hprime, n, CAP);
        gather_kernel<<<NB, 1024, 0, stream>>>(packed, cursor, hprime, deg, bias, out, n, CAP);
    } else {
        // fallback: atomic path (slow but correct, tiny ws)
        float* accfb = (float*)(ws + off_accfb);
        hipMemsetAsync(ws, 0, off_cursor, stream);    // zero deg + hprime + accfb
        deg_atomic_kernel<<<(e4 + 255) / 256, 256, 0, stream>>>(dst, deg, e4);
        gemv_scaled_kernel<<<(n + 3) / 4, 256, 0, stream>>>(x, W, deg, hprime, n);
        scatter_kernel<<<(e4 + 255) / 256, 256, 0, stream>>>(src, dst, hprime, accfb, e4);
        final_kernel<<<(n + 255) / 256, 256, 0, stream>>>(hprime, accfb, deg, bias, out, n);
    }
}